// Round 3
// baseline (907.485 us; speedup 1.0000x reference)
//
#include <hip/hip_runtime.h>
#include <math.h>

// CTC loss, T=1024 B=64 V=256 L=256.
//  - LINEAR-domain recursion on RAW logits (softmax denominator deferred: it's a
//    per-(t,b) additive constant in log domain -> factors out).
//  - cumlse[b] = sum_t logsumexp_v(logits[t,b,:]) computed by the non-recursion
//    blocks of the same kernel (massively parallel, hidden behind recursion).
//  - Recursion truncated to S_b = 2*label_len[b]+1 (mass flows left->right only;
//    keeps renorm max over relevant states).
//  - ONE barrier per time step:
//      * e-row staging uses a 2-deep register ping-pong pipeline (load row t+3 at
//        step t, exp+ds_write at step t+2) so no vmcnt wait sits on the step path.
//      * renorm max (every 8 steps) is published via redbuf and APPLIED one step
//        later, folded into that step's multiply -> no extra barrier.
//  - loss_b = cumlse[b] - ( ln(a[end]+a[end-1]) + ln2*log2acc )

constexpr int V = 256;
constexpr float LN2_F = 0.6931471805599453f;

__global__ __launch_bounds__(512) void ctc_main(
    const int*   __restrict__ labels,      // [B, L]
    const float* __restrict__ logits,      // [T, B, V]
    const int*   __restrict__ label_len,   // [B]
    const int*   __restrict__ logit_len,   // [B]
    float*       __restrict__ cumlse,      // [B] (pre-zeroed, atomicAdd)
    float*       __restrict__ lnterm,      // [B]
    int T, int B, int L)
{
    const int tid = threadIdx.x;

    if ((int)blockIdx.x < B) {
        // ================= recursion block: one batch element =================
        const int b = blockIdx.x;
        __shared__ float a_buf[2][514];   // alpha double buffer
        __shared__ float e_row[3][V];     // exp(raw logit) rows, triple buffer
        __shared__ float redbuf[8];       // per-wave max, read one step later

        const int Tb = logit_len[b];
        const int Lb = label_len[b];
        const int Sb = 2 * Lb + 1;        // truncated state count
        const int s  = tid;
        const bool active = (s < Sb);
        const bool has512 = (Sb > 512) && (tid == 511);  // state 512 rider

        int  myidx  = 0;
        bool skipok = false;
        if (active && (s & 1)) {
            const int li = s >> 1;
            myidx  = labels[b * L + li];
            skipok = (s >= 3) ? (myidx != labels[b * L + li - 1]) : true;
        }

        const float* lg = logits + (size_t)b * V;     // row t at lg + t*rowstride
        const size_t rowstride = (size_t)B * V;

        // t = 0 init: only states 0,1 reachable
        float cur  = 0.f;
        float cur2 = 0.f;                              // state 512 (if has512)
        if (active && s < 2) cur = __expf(lg[myidx]);

        // e-row pipeline: wave 0 stages rows as float4 (16B/lane x 64 lanes)
        float4 rp[2];
        if (tid < 64) {
            if (Tb >= 2) {
                float4 x = ((const float4*)(lg + rowstride * 1))[tid];
                e_row[1][tid * 4 + 0] = __expf(x.x);
                e_row[1][tid * 4 + 1] = __expf(x.y);
                e_row[1][tid * 4 + 2] = __expf(x.z);
                e_row[1][tid * 4 + 3] = __expf(x.w);
            }
            const int r2 = min(2, Tb - 1), r3 = min(3, Tb - 1);
            rp[1] = ((const float4*)(lg + rowstride * r2))[tid];  // consumed t=1
            rp[0] = ((const float4*)(lg + rowstride * r3))[tid];  // consumed t=2
        }

        float log2acc = 0.f;
        int p = 0;
        for (int t = 1; t < Tb; ++t) {
            // ---- region A: stage alpha; stage e-row t+1 from 2-step-old reg ----
            if (active) a_buf[p][s] = cur;
            if (tid < 64) {
                const float4 x = rp[t & 1];
                float* er = e_row[(t + 1) % 3];
                er[tid * 4 + 0] = __expf(x.x);
                er[tid * 4 + 1] = __expf(x.y);
                er[tid * 4 + 2] = __expf(x.z);
                er[tid * 4 + 3] = __expf(x.w);
                const int rn = min(t + 3, Tb - 1);    // issue load for step t+2
                rp[t & 1] = ((const float4*)(lg + rowstride * rn))[tid];
            }
            __syncthreads();
            // ---- region B: recurrence update ----
            const float* er = e_row[t % 3];
            const bool applyrn = ((t & 7) == 0);       // t>=8 since t starts at 1
            float Minv = 1.f, Mval = 1.f;
            if (applyrn) {
                float M = 1e-30f;
                #pragma unroll
                for (int w = 0; w < 8; ++w) M = fmaxf(M, redbuf[w]);
                Mval = M;
                Minv = 1.f / M;
            }
            if (active) {
                const float nm1 = (s >= 1) ? a_buf[p][s - 1] : 0.f;
                const float nm2 = (s >= 2 && skipok) ? a_buf[p][s - 2] : 0.f;
                const float ev  = er[myidx];
                if (has512) {
                    // state 512: needs old a[511] (=cur) and a[510] (=nm1)
                    cur2 = (cur2 + cur + nm1) * er[0];
                }
                cur = (cur + nm1 + nm2) * ev;
            }
            if (applyrn) {
                cur  *= Minv;
                cur2 *= Minv;
                log2acc += log2f(Mval);
            }
            if ((t & 7) == 7) {                        // publish max for t+1
                float m = fmaxf(cur, cur2);
                #pragma unroll
                for (int o = 32; o >= 1; o >>= 1) m = fmaxf(m, __shfl_xor(m, o, 64));
                if ((tid & 63) == 0) redbuf[tid >> 6] = m;
            }
            p ^= 1;
        }

        // ---- finalize ----
        if (active) a_buf[p][s] = cur;
        if (has512) a_buf[p][512] = cur2;
        __syncthreads();
        if (tid == 0) {
            const int end = 2 * Lb;                    // == Sb-1
            const int em1 = (end > 0) ? end - 1 : 0;
            float ssum = a_buf[p][end] + a_buf[p][em1];
            ssum = fmaxf(ssum, 1e-37f);                // inf-protection only
            lnterm[b] = logf(ssum) + LN2_F * log2acc;
        }
    } else {
        // ================= lse blocks: cumlse[b] += lse(logits[t,b,:]) =========
        const int lb   = blockIdx.x - B;
        const int wave = tid >> 6;
        const int lane = tid & 63;
        const int wavesPerBlock = blockDim.x >> 6;            // 8
        const int nLseBlocks    = gridDim.x - B;
        const int totalWaves    = nLseBlocks * wavesPerBlock;
        const int rows = T * B;
        for (int r = lb * wavesPerBlock + wave; r < rows; r += totalWaves) {
            const int t  = r / B;
            const int bb = r - t * B;
            const float4 x = ((const float4*)(logits + (size_t)r * V))[lane];
            float m = fmaxf(fmaxf(x.x, x.y), fmaxf(x.z, x.w));
            #pragma unroll
            for (int o = 32; o >= 1; o >>= 1) m = fmaxf(m, __shfl_xor(m, o, 64));
            float ss = __expf(x.x - m) + __expf(x.y - m) +
                       __expf(x.z - m) + __expf(x.w - m);
            #pragma unroll
            for (int o = 32; o >= 1; o >>= 1) ss += __shfl_xor(ss, o, 64);
            if (lane == 0 && t < logit_len[bb]) {
                atomicAdd(&cumlse[bb], m + logf(ss));
            }
        }
    }
}

__global__ __launch_bounds__(64) void ctc_final(
    const float* __restrict__ cumlse,
    const float* __restrict__ lnterm,
    float* __restrict__ out, int B)
{
    const int b = threadIdx.x;
    float v = (b < B) ? (cumlse[b] - lnterm[b]) : 0.f;
    #pragma unroll
    for (int o = 32; o >= 1; o >>= 1) v += __shfl_xor(v, o, 64);
    if (threadIdx.x == 0) out[0] = v / (float)B;
}

extern "C" void kernel_launch(void* const* d_in, const int* in_sizes, int n_in,
                              void* d_out, int out_size, void* d_ws, size_t ws_size,
                              hipStream_t stream) {
    const int*   labels    = (const int*)d_in[0];
    const float* logits    = (const float*)d_in[1];
    const int*   label_len = (const int*)d_in[2];
    const int*   logit_len = (const int*)d_in[3];

    const int B = in_sizes[2];                 // 64
    const int L = in_sizes[0] / B;             // 256
    const int T = in_sizes[1] / (B * V);       // 1024

    float* cumlse = (float*)d_ws;              // [B]
    float* lnterm = cumlse + B;                // [B]

    hipMemsetAsync(cumlse, 0, B * sizeof(float), stream);

    const int nLse = 192;                      // 64 + 192 = 256 blocks = 1/CU
    ctc_main<<<B + nLse, 512, 0, stream>>>(labels, logits, label_len, logit_len,
                                           cumlse, lnterm, T, B, L);
    ctc_final<<<1, 64, 0, stream>>>(cumlse, lnterm, (float*)d_out, B);
}

// Round 4
// 618.939 us; speedup vs baseline: 1.4662x; 1.4662x over previous
//
#include <hip/hip_runtime.h>
#include <math.h>

// CTC loss, T=1024 B=64 V=256 L=256.
//  - LINEAR-domain recursion on RAW logits (softmax denominator deferred: it's a
//    per-(t,b) additive constant in log domain -> factors out).
//  - cumlse[b] = sum_t logsumexp_v(logits[t,b,:]) computed by the non-recursion
//    blocks of the same kernel (massively parallel, hidden behind recursion).
//  - Recursion truncated to S_b = 2*label_len[b]+1 (mass flows left->right only).
//  - ONE manual barrier per time step: `s_waitcnt lgkmcnt(0); s_barrier`.
//    __syncthreads() would emit s_waitcnt vmcnt(0) and DRAIN wave 0's in-flight
//    logit-row loads every step (~900 cyc HBM latency on the critical path —
//    measured 1850 cyc/step in rounds 2-3). The manual barrier waits only on
//    LDS; the register-targeted global loads stay in flight across barriers
//    (consumed 2 steps later with compiler-inserted vmcnt(1)).
//  - Renorm every 8 steps; max published via redbuf, applied one step later.
//  - loss_b = cumlse[b] - ( ln(a[end]+a[end-1]) + ln2*log2acc )

constexpr int V = 256;
constexpr float LN2_F = 0.6931471805599453f;

// Barrier with LDS-only wait: does NOT drain outstanding global loads (vmcnt).
__device__ __forceinline__ void sync_lds_only() {
    __asm__ volatile("s_waitcnt lgkmcnt(0)\n\ts_barrier" ::: "memory");
}

__global__ __launch_bounds__(512) void ctc_main(
    const int*   __restrict__ labels,      // [B, L]
    const float* __restrict__ logits,      // [T, B, V]
    const int*   __restrict__ label_len,   // [B]
    const int*   __restrict__ logit_len,   // [B]
    float*       __restrict__ cumlse,      // [B] (pre-zeroed, atomicAdd)
    float*       __restrict__ lnterm,      // [B]
    int T, int B, int L)
{
    const int tid = threadIdx.x;

    if ((int)blockIdx.x < B) {
        // ================= recursion block: one batch element =================
        const int b = blockIdx.x;
        __shared__ float a_buf[2][514];   // alpha double buffer
        __shared__ float e_row[3][V];     // exp(raw logit) rows, triple buffer
        __shared__ float redbuf[8];       // per-wave max, read one step later

        const int Tb = logit_len[b];
        const int Lb = label_len[b];
        const int Sb = 2 * Lb + 1;        // truncated state count
        const int s  = tid;
        const bool active = (s < Sb);
        const bool has512 = (Sb > 512) && (tid == 511);  // state 512 rider

        int  myidx  = 0;
        bool skipok = false;
        if (active && (s & 1)) {
            const int li = s >> 1;
            myidx  = labels[b * L + li];
            skipok = (s >= 3) ? (myidx != labels[b * L + li - 1]) : true;
        }

        const float* lg = logits + (size_t)b * V;     // row t at lg + t*rowstride
        const size_t rowstride = (size_t)B * V;

        // t = 0 init: only states 0,1 reachable
        float cur  = 0.f;
        float cur2 = 0.f;                              // state 512 (if has512)
        if (active && s < 2) cur = __expf(lg[myidx]);
        if (active) a_buf[0][s] = cur;                 // stage alpha(t=0)

        // e-row pipeline: wave 0 stages rows as float4 (16B/lane x 64 lanes)
        float4 rp[2];
        if (tid < 64) {
            if (Tb >= 2) {
                float4 x = ((const float4*)(lg + rowstride * 1))[tid];
                e_row[1][tid * 4 + 0] = __expf(x.x);
                e_row[1][tid * 4 + 1] = __expf(x.y);
                e_row[1][tid * 4 + 2] = __expf(x.z);
                e_row[1][tid * 4 + 3] = __expf(x.w);
            }
            const int r2 = min(2, Tb - 1), r3 = min(3, Tb - 1);
            rp[1] = ((const float4*)(lg + rowstride * r2))[tid];  // consumed t=1
            rp[0] = ((const float4*)(lg + rowstride * r3))[tid];  // consumed t=2
        }

        float log2acc = 0.f;
        int p = 0;
        for (int t = 1; t < Tb; ++t) {
            sync_lds_only();   // orders previous interval's LDS writes; no vmcnt
            // ---- recurrence update (reads prev-interval LDS) ----
            const float* er = e_row[t % 3];
            const bool applyrn = ((t & 7) == 0);
            float Minv = 1.f, Mval = 1.f;
            if (applyrn) {
                float M = 1e-30f;
                #pragma unroll
                for (int w = 0; w < 8; ++w) M = fmaxf(M, redbuf[w]);
                Mval = M;
                Minv = 1.f / M;
            }
            if (active) {
                const float nm1 = (s >= 1) ? a_buf[p][s - 1] : 0.f;
                const float nm2 = (s >= 2 && skipok) ? a_buf[p][s - 2] : 0.f;
                const float ev  = er[myidx];
                if (has512) {
                    // state 512: needs old a[511] (=cur) and a[510] (=nm1)
                    cur2 = (cur2 + cur + nm1) * er[0];
                }
                cur = (cur + nm1 + nm2) * ev;
            }
            if (applyrn) {
                cur  *= Minv;
                cur2 *= Minv;
                log2acc += log2f(Mval);
            }
            if (active) a_buf[p ^ 1][s] = cur;         // stage alpha for t+1
            if ((t & 7) == 7) {                        // publish max for t+1
                float m = fmaxf(cur, cur2);
                #pragma unroll
                for (int o = 32; o >= 1; o >>= 1) m = fmaxf(m, __shfl_xor(m, o, 64));
                if ((tid & 63) == 0) redbuf[tid >> 6] = m;
            }
            // ---- wave 0: stage e-row t+1 from 2-step-old regs; load t+3 ----
            if (tid < 64) {
                const float4 x = rp[t & 1];
                float* erw = e_row[(t + 1) % 3];
                erw[tid * 4 + 0] = __expf(x.x);
                erw[tid * 4 + 1] = __expf(x.y);
                erw[tid * 4 + 2] = __expf(x.z);
                erw[tid * 4 + 3] = __expf(x.w);
                const int rn = min(t + 3, Tb - 1);
                rp[t & 1] = ((const float4*)(lg + rowstride * rn))[tid];
            }
            p ^= 1;
        }

        // ---- finalize: a_buf[p] holds final alpha (written in last iter) ----
        if (has512) a_buf[p][512] = cur2;
        __syncthreads();                               // full drain OK (once)
        if (tid == 0) {
            const int end = 2 * Lb;                    // == Sb-1
            const int em1 = (end > 0) ? end - 1 : 0;
            float ssum = a_buf[p][end] + a_buf[p][em1];
            ssum = fmaxf(ssum, 1e-37f);                // inf-protection only
            lnterm[b] = logf(ssum) + LN2_F * log2acc;
        }
    } else {
        // ================= lse blocks: cumlse[b] += lse(logits[t,b,:]) =========
        const int lb   = blockIdx.x - B;
        const int wave = tid >> 6;
        const int lane = tid & 63;
        const int wavesPerBlock = blockDim.x >> 6;            // 8
        const int nLseBlocks    = gridDim.x - B;
        const int totalWaves    = nLseBlocks * wavesPerBlock;
        const int rows = T * B;
        // Per-wave accumulation: rows for one wave share the same b when
        // totalWaves % B == 0; flush-on-change keeps it general. One atomicAdd
        // per (wave, b) instead of per row.
        float acc = 0.f;
        int   cb  = -1;
        for (int r = lb * wavesPerBlock + wave; r < rows; r += totalWaves) {
            const int t  = r / B;
            const int bb = r - t * B;
            const float4 x = ((const float4*)(logits + (size_t)r * V))[lane];
            float m = fmaxf(fmaxf(x.x, x.y), fmaxf(x.z, x.w));
            #pragma unroll
            for (int o = 32; o >= 1; o >>= 1) m = fmaxf(m, __shfl_xor(m, o, 64));
            float ss = __expf(x.x - m) + __expf(x.y - m) +
                       __expf(x.z - m) + __expf(x.w - m);
            #pragma unroll
            for (int o = 32; o >= 1; o >>= 1) ss += __shfl_xor(ss, o, 64);
            if (bb != cb) {
                if (lane == 0 && cb >= 0) atomicAdd(&cumlse[cb], acc);
                acc = 0.f;
                cb  = bb;
            }
            if (t < logit_len[bb]) acc += m + logf(ss);
        }
        if (lane == 0 && cb >= 0) atomicAdd(&cumlse[cb], acc);
    }
}

__global__ __launch_bounds__(64) void ctc_final(
    const float* __restrict__ cumlse,
    const float* __restrict__ lnterm,
    float* __restrict__ out, int B)
{
    const int b = threadIdx.x;
    float v = (b < B) ? (cumlse[b] - lnterm[b]) : 0.f;
    #pragma unroll
    for (int o = 32; o >= 1; o >>= 1) v += __shfl_xor(v, o, 64);
    if (threadIdx.x == 0) out[0] = v / (float)B;
}

extern "C" void kernel_launch(void* const* d_in, const int* in_sizes, int n_in,
                              void* d_out, int out_size, void* d_ws, size_t ws_size,
                              hipStream_t stream) {
    const int*   labels    = (const int*)d_in[0];
    const float* logits    = (const float*)d_in[1];
    const int*   label_len = (const int*)d_in[2];
    const int*   logit_len = (const int*)d_in[3];

    const int B = in_sizes[2];                 // 64
    const int L = in_sizes[0] / B;             // 256
    const int T = in_sizes[1] / (B * V);       // 1024

    float* cumlse = (float*)d_ws;              // [B]
    float* lnterm = cumlse + B;                // [B]

    hipMemsetAsync(cumlse, 0, B * sizeof(float), stream);

    const int nLse = 192;                      // 64 + 192 = 256 blocks = 1/CU
    ctc_main<<<B + nLse, 512, 0, stream>>>(labels, logits, label_len, logit_len,
                                           cumlse, lnterm, T, B, L);
    ctc_final<<<1, 64, 0, stream>>>(cumlse, lnterm, (float*)d_out, B);
}

// Round 5
// 397.524 us; speedup vs baseline: 2.2828x; 1.5570x over previous
//
#include <hip/hip_runtime.h>
#include <math.h>

// CTC loss, T=1024 B=64 V=256 L=256 (S=513).
// Round-5 design: ONE WAVE per batch element, ZERO barriers.
//  - lane i holds states 8i..8i+7 in registers; state 512 rides on lane 63.
//    Cross-lane neighbor values via __shfl_up (2 per step).
//  - LINEAR-domain recursion on RAW logits (softmax denominator deferred; it is
//    a per-(t,b) additive constant in log space -> factors out).
//  - e-row pipeline (same wave, no barriers):
//      * float4 global load of row t+9 into an 8-deep register ring (vmcnt(7)
//        waits only; ~8 steps of HBM latency hiding),
//      * ds_write_b128 row t+1 into ping-pong LDS row, gather 5 raw values
//        (blank + 4 label indices) for step t+1, consumed NEXT iteration
//        (same-wave DS ops are in-order; compiler emits cheap lgkmcnt(N)).
//  - Renorm every 8 steps, DEFERRED one window: butterfly max published at
//    window k is applied at window k+1 with an extra 2^-16 downshift
//    (self-stabilizing; exact accounting in log2acc at apply time).
//  - Truncation to S_b = 2*label_len+1 via per-state 0/1 masks (padded-label
//    states would otherwise dominate the renorm max by ~e^300).
//  - loss_b = cumlse[b] - ( ln(a[end]+a[end-1]) + ln2*log2acc )
//  - cumlse[b] = sum_t logsumexp_v(logits[t,b,:]) by the lse blocks (blockIdx
//    >= B) of the same kernel, depth-1 prefetch, one atomicAdd per (wave,b).

constexpr int V = 256;
constexpr float LN2_F = 0.6931471805599453f;

__global__ __launch_bounds__(256) void ctc_main(
    const int*   __restrict__ labels,      // [B, L]
    const float* __restrict__ logits,      // [T, B, V]
    const int*   __restrict__ label_len,   // [B]
    const int*   __restrict__ logit_len,   // [B]
    float*       __restrict__ cumlse,      // [B] (pre-zeroed, atomicAdd)
    float*       __restrict__ lnterm,      // [B]
    int T, int B, int L)
{
    const int tid = threadIdx.x;

    if ((int)blockIdx.x < B) {
        if (tid >= 64) return;            // recursion block = 1 wave
        const int b = blockIdx.x;
        const int l = tid;
        __shared__ float erow[2][V];      // raw logit row, ping-pong
        __shared__ float afin[514];       // final alpha for readout

        const int Tb = logit_len[b];
        const int Lb = label_len[b];
        const int Sb = 2 * Lb + 1;

        const float* lg = logits + (size_t)b * V;
        const size_t rs = (size_t)B * V;

        // labels for this lane: odd states 8l+1,3,5,7 emit labels[4l+0..3]
        const int4 lb4 = ((const int4*)(labels + (size_t)b * L))[l];
        int prevw = __shfl_up(lb4.w, 1);            // labels[4l-1]
        const float sk1 = (l > 0 && lb4.x != prevw) ? 1.f : 0.f;
        const float sk3 = (lb4.y != lb4.x) ? 1.f : 0.f;
        const float sk5 = (lb4.z != lb4.y) ? 1.f : 0.f;
        const float sk7 = (lb4.w != lb4.z) ? 1.f : 0.f;

        float mk[8];
        #pragma unroll
        for (int j = 0; j < 8; ++j) mk[j] = (8 * l + j < Sb) ? 1.f : 0.f;
        const float mk512 = (Sb > 512 && l == 63) ? 1.f : 0.f;

        // t=0 init: states 0,1 only
        float cur[8], cur2 = 0.f;
        #pragma unroll
        for (int j = 0; j < 8; ++j) cur[j] = 0.f;
        if (l == 0) {
            cur[0] = __expf(lg[0]);
            cur[1] = __expf(lg[lb4.x]) * mk[1];
        }

        // prologue: stage row 1 into erow[1], gather raw values for t=1
        float geb = 0.f, g1 = 0.f, g3 = 0.f, g5 = 0.f, g7 = 0.f;
        if (Tb >= 2) {
            ((float4*)erow[1])[l] = ((const float4*)(lg + rs))[l];
            geb = erow[1][0];
            g1 = erow[1][lb4.x]; g3 = erow[1][lb4.y];
            g5 = erow[1][lb4.z]; g7 = erow[1][lb4.w];
        }
        // ring: rp[(t+1)&7] holds row t+1; prefill rows 2..9 (clamped)
        float4 rp[8];
        #pragma unroll
        for (int j = 2; j <= 9; ++j) {
            const int r = (j < Tb) ? j : (Tb - 1);
            rp[j & 7] = ((const float4*)(lg + rs * r))[l];
        }

        float log2acc = 0.f;
        float Mpend = 1.f;                 // pending renorm scale (deferred)
        for (int tb = 0; tb * 8 < Tb; ++tb) {
            #pragma unroll
            for (int u = 0; u < 8; ++u) {
                const int t = 8 * tb + u;
                if (t >= Tb) break;
                if (t == 0) continue;      // t=0 handled by init/prologue
                // ---- stage row t+1; issue gathers for t+1; prefetch t+9 ----
                const int slot = (u + 1) & 7;        // == (t+1)&7
                float* er = erow[(t + 1) & 1];
                ((float4*)er)[l] = rp[slot];
                int rn = t + 9; if (rn > Tb - 1) rn = Tb - 1;
                rp[slot] = ((const float4*)(lg + rs * rn))[l];
                const float ngb = er[0];
                const float n1 = er[lb4.x], n3 = er[lb4.y];
                const float n5 = er[lb4.z], n7 = er[lb4.w];
                // ---- consume step-t e-values (gathered last iteration) ----
                const float xb = __expf(geb);
                const float x1 = __expf(g1), x3 = __expf(g3);
                const float x5 = __expf(g5), x7 = __expf(g7);
                float c7m = __shfl_up(cur[7], 1);
                float c6m = __shfl_up(cur[6], 1);
                if (l == 0) { c7m = 0.f; c6m = 0.f; }
                // descending update: each uses OLD lower-indexed values.
                // Even states (blank): self + s-1 only. Odd: + skip via sk*.
                cur2   = (cur2 + cur[7]) * xb * mk512;      // state 512 (blank)
                cur[7] = (cur[7] + cur[6] + sk7 * cur[5]) * x7 * mk[7];
                cur[6] = (cur[6] + cur[5]) * xb * mk[6];
                cur[5] = (cur[5] + cur[4] + sk5 * cur[3]) * x5 * mk[5];
                cur[4] = (cur[4] + cur[3]) * xb * mk[4];
                cur[3] = (cur[3] + cur[2] + sk3 * cur[1]) * x3 * mk[3];
                cur[2] = (cur[2] + cur[1]) * xb * mk[2];
                cur[1] = (cur[1] + cur[0] + sk1 * c7m) * x1 * mk[1];
                cur[0] = (cur[0] + c7m) * xb * mk[0];
                // ---- deferred renorm: apply pending scale, publish new ----
                if (u == 7) {
                    const float inv = (1.0f / Mpend) * 0x1p-16f;
                    cur2 *= inv;
                    #pragma unroll
                    for (int j = 0; j < 8; ++j) cur[j] *= inv;
                    log2acc += log2f(Mpend) + 16.f;
                    float m = cur2;
                    #pragma unroll
                    for (int j = 0; j < 8; ++j) m = fmaxf(m, cur[j]);
                    #pragma unroll
                    for (int o = 1; o <= 32; o <<= 1)
                        m = fmaxf(m, __shfl_xor(m, o, 64));
                    Mpend = fmaxf(m, 1e-30f);   // applied next window
                }
                geb = ngb; g1 = n1; g3 = n3; g5 = n5; g7 = n7;
            }
        }

        // ---- readout: ln(a[end]+a[end-1]) + ln2*log2acc ----
        // (pending Mpend is neither applied to cur nor counted -> consistent)
        #pragma unroll
        for (int j = 0; j < 8; ++j) afin[8 * l + j] = cur[j];
        if (l == 63) afin[512] = cur2;
        const int end = 2 * Lb;
        const int em1 = (end > 0) ? end - 1 : 0;
        float ssum = afin[end] + afin[em1];     // same-wave DS, in-order
        ssum = fmaxf(ssum, 1e-37f);             // inf-protection only
        if (l == 0) lnterm[b] = logf(ssum) + LN2_F * log2acc;
    } else {
        // ============ lse blocks: cumlse[b] += lse(logits[t,b,:]) ============
        const int lane = tid & 63;
        const int w = (blockIdx.x - B) * 4 + (tid >> 6);
        const int nW = (gridDim.x - B) * 4;
        const int rows = T * B;
        float acc = 0.f;
        int   cb  = -1;
        int r = w;
        if (r >= rows) return;
        float4 nxt = ((const float4*)(logits + (size_t)r * V))[lane];
        while (true) {
            const int rn = r + nW;
            const bool more = rn < rows;
            const float4 x = nxt;
            if (more) nxt = ((const float4*)(logits + (size_t)rn * V))[lane];
            float m = fmaxf(fmaxf(x.x, x.y), fmaxf(x.z, x.w));
            #pragma unroll
            for (int o = 32; o >= 1; o >>= 1) m = fmaxf(m, __shfl_xor(m, o, 64));
            float ss = __expf(x.x - m) + __expf(x.y - m) +
                       __expf(x.z - m) + __expf(x.w - m);
            #pragma unroll
            for (int o = 32; o >= 1; o >>= 1) ss += __shfl_xor(ss, o, 64);
            const int t  = r / B;
            const int bb = r - t * B;
            if (bb != cb) {
                if (lane == 0 && cb >= 0) atomicAdd(&cumlse[cb], acc);
                acc = 0.f;
                cb  = bb;
            }
            if (t < logit_len[bb]) acc += m + logf(ss);
            if (!more) break;
            r = rn;
        }
        if (lane == 0 && cb >= 0) atomicAdd(&cumlse[cb], acc);
    }
}

__global__ __launch_bounds__(64) void ctc_final(
    const float* __restrict__ cumlse,
    const float* __restrict__ lnterm,
    float* __restrict__ out, int B)
{
    const int b = threadIdx.x;
    float v = (b < B) ? (cumlse[b] - lnterm[b]) : 0.f;
    #pragma unroll
    for (int o = 32; o >= 1; o >>= 1) v += __shfl_xor(v, o, 64);
    if (threadIdx.x == 0) out[0] = v / (float)B;
}

extern "C" void kernel_launch(void* const* d_in, const int* in_sizes, int n_in,
                              void* d_out, int out_size, void* d_ws, size_t ws_size,
                              hipStream_t stream) {
    const int*   labels    = (const int*)d_in[0];
    const float* logits    = (const float*)d_in[1];
    const int*   label_len = (const int*)d_in[2];
    const int*   logit_len = (const int*)d_in[3];

    const int B = in_sizes[2];                 // 64
    const int L = in_sizes[0] / B;             // 256
    const int T = in_sizes[1] / (B * V);       // 1024

    float* cumlse = (float*)d_ws;              // [B]
    float* lnterm = cumlse + B;                // [B]

    hipMemsetAsync(cumlse, 0, B * sizeof(float), stream);

    const int nLse = 256;                      // 1024 lse waves -> 64 rows each
    ctc_main<<<B + nLse, 256, 0, stream>>>(labels, logits, label_len, logit_len,
                                           cumlse, lnterm, T, B, L);
    ctc_final<<<1, 64, 0, stream>>>(cumlse, lnterm, (float*)d_out, B);
}